// Round 1
// baseline (1142.415 us; speedup 1.0000x reference)
//
#include <hip/hip_runtime.h>
#include <cmath>

// Problem constants
#define NCH   256      // DIM
#define NH    8
#define HD    32
#define HWDIM 56
#define NPIX  3136     // 56*56
#define NB    32
#define INV_N (1.0f / 3136.0f)

// ws layout (floats): kv[32][8][32][32] at 0 (262144), km[32][8][32] at 262144 (8192)
#define KV_FLOATS 262144
#define KM_FLOATS 8192

// ---------------------------------------------------------------------------
// Kernel 1: compute K = elu(conv1x1_k(x))+1 per tile, accumulate kv = K V^T
// and kmean via atomics. Grid: (16 chunks of 196 pos, 32 batches), 256 thr.
// Thread t owns k-channel t (head h = t>>5, d = t&31).
// ---------------------------------------------------------------------------
__global__ __launch_bounds__(256, 2)
void kv_kernel(const float* __restrict__ x, const float* __restrict__ qk_w,
               const float* __restrict__ qk_b, float* __restrict__ kv,
               float* __restrict__ km) {
  const int b = blockIdx.y;
  const int chunk = blockIdx.x;
  const int t = threadIdx.x;
  const int h = t >> 5, d = t & 31;

  __shared__ float xs[256][52];   // 49 used, padded; rows 16B-aligned (52*4=208)

  float kvacc[32];
#pragma unroll
  for (int e = 0; e < 32; ++e) kvacc[e] = 0.f;
  float kmacc = 0.f;

  const float bias = qk_b[256 + t];
  const float* wrow = qk_w + (size_t)(256 + t) * 128;

  for (int st = 0; st < 4; ++st) {
    const int p0 = chunk * 196 + st * 49;
    __syncthreads();
    for (int i = t; i < 256 * 49; i += 256) {
      int cc = i / 49, pp = i - cc * 49;
      xs[cc][pp] = x[((size_t)b * NCH + cc) * NPIX + p0 + pp];
    }
    __syncthreads();

    // conv: acc[p] = sum_kk w[kk] * x1[kk][p]
    float acc[49];
#pragma unroll
    for (int p = 0; p < 49; ++p) acc[p] = 0.f;
    for (int kb = 0; kb < 8; ++kb) {
      float wreg[16];
#pragma unroll
      for (int q4 = 0; q4 < 4; ++q4) {
        float4 wv = *(const float4*)&wrow[kb * 16 + q4 * 4];
        wreg[4 * q4 + 0] = wv.x; wreg[4 * q4 + 1] = wv.y;
        wreg[4 * q4 + 2] = wv.z; wreg[4 * q4 + 3] = wv.w;
      }
#pragma unroll
      for (int k2 = 0; k2 < 16; ++k2) {
        const float w = wreg[k2];
        const float4* xr4 = (const float4*)&xs[128 + kb * 16 + k2][0];
#pragma unroll
        for (int p4 = 0; p4 < 12; ++p4) {
          float4 xv = xr4[p4];
          acc[4 * p4 + 0] += w * xv.x; acc[4 * p4 + 1] += w * xv.y;
          acc[4 * p4 + 2] += w * xv.z; acc[4 * p4 + 3] += w * xv.w;
        }
        acc[48] += w * xs[128 + kb * 16 + k2][48];
      }
    }
    // elu + 1 (in place), kmean
#pragma unroll
    for (int p = 0; p < 49; ++p) {
      float v = acc[p] + bias;
      v = (v > 0.f) ? (v + 1.f) : expf(v);
      acc[p] = v;
      kmacc += v;
    }
    // kv accumulation: kvacc[e] += sum_p K[p] * V[e][p]
#pragma unroll
    for (int e = 0; e < 32; ++e) {
      const float4* vr4 = (const float4*)&xs[h * 32 + e][0];
      float s = 0.f;
#pragma unroll
      for (int p4 = 0; p4 < 12; ++p4) {
        float4 vv = vr4[p4];
        s += acc[4 * p4 + 0] * vv.x + acc[4 * p4 + 1] * vv.y +
             acc[4 * p4 + 2] * vv.z + acc[4 * p4 + 3] * vv.w;
      }
      s += acc[48] * xs[h * 32 + e][48];
      kvacc[e] += s;
    }
  }

  float* kvp = kv + (((size_t)b * NH + h) * HD + d) * HD;
#pragma unroll
  for (int e = 0; e < 32; ++e) atomicAdd(&kvp[e], kvacc[e]);
  atomicAdd(&km[((size_t)b * NH + h) * HD + d], kmacc);
}

// ---------------------------------------------------------------------------
// Kernel 2: Q = elu(conv1x1_q(x))+1, out = (Q^T kv)/(Q^T kmean + eps) + pe
// Grid: (28 chunks of 2 rows, 32 batches), 256 threads.
// ---------------------------------------------------------------------------
__global__ __launch_bounds__(256)
void out_kernel(const float* __restrict__ x, const float* __restrict__ qk_w,
                const float* __restrict__ qk_b, const float* __restrict__ pe_w,
                const float* __restrict__ pe_b, const float* __restrict__ kvg,
                const float* __restrict__ kmg, float* __restrict__ out) {
  const int b = blockIdx.y;
  const int row0 = blockIdx.x * 2;
  const int t = threadIdx.x;

  __shared__ float x0[128][56];     // q-side input channels, one image row
  __shared__ float Qs[64][56];      // Q for current head-pair
  __shared__ float kvs[2][32][32];  // kv for current head-pair (pre-scaled)
  __shared__ float kms[64];         // kmean for current head-pair (pre-scaled)

  for (int row = row0; row < row0 + 2; ++row) {
    __syncthreads();
    for (int i = t; i < 128 * 56; i += 256) {
      int cc = i / 56, pp = i - cc * 56;
      x0[cc][pp] = x[((size_t)b * NCH + cc) * NPIX + row * HWDIM + pp];
    }
    for (int hp = 0; hp < 4; ++hp) {
      __syncthreads();  // x0 ready / previous phase B done
      // stage kv + kmean for heads 2hp, 2hp+1
      {
        const float* src = kvg + ((size_t)b * NH + hp * 2) * HD * HD;
        for (int i = t; i < 2048; i += 256) ((float*)kvs)[i] = src[i] * INV_N;
        const float* srcm = kmg + ((size_t)b * NH + hp * 2) * HD;
        if (t < 64) kms[t] = srcm[t] * INV_N;
      }
      // phase A: Q for channels hp*64 .. hp*64+63
      {
        const int cl = t >> 2;
        const int c = hp * 64 + cl;
        const int psub = t & 3;
        const float* wrow = qk_w + (size_t)c * 128;
        float acc[14];
#pragma unroll
        for (int i = 0; i < 14; ++i) acc[i] = 0.f;
        for (int kb = 0; kb < 8; ++kb) {
          float wreg[16];
#pragma unroll
          for (int q4 = 0; q4 < 4; ++q4) {
            float4 wv = *(const float4*)&wrow[kb * 16 + q4 * 4];
            wreg[4 * q4 + 0] = wv.x; wreg[4 * q4 + 1] = wv.y;
            wreg[4 * q4 + 2] = wv.z; wreg[4 * q4 + 3] = wv.w;
          }
#pragma unroll
          for (int k2 = 0; k2 < 16; ++k2) {
            const float w = wreg[k2];
            const float* xr = &x0[kb * 16 + k2][psub * 14];
#pragma unroll
            for (int i2 = 0; i2 < 7; ++i2) {
              float2 xv = *(const float2*)&xr[i2 * 2];
              acc[2 * i2 + 0] += w * xv.x;
              acc[2 * i2 + 1] += w * xv.y;
            }
          }
        }
        const float bias = qk_b[c];
#pragma unroll
        for (int i = 0; i < 14; ++i) {
          float v = acc[i] + bias;
          Qs[cl][psub * 14 + i] = (v > 0.f) ? (v + 1.f) : expf(v);
        }
      }
      __syncthreads();
      // phase B: outputs for 64 channels of this head-pair at this row
      if (t < 224) {
        const int p = t % 56;
        const int cg = t / 56;        // 0..3
        const int hl = cg >> 1;       // local head 0..1
        const int e0 = (cg & 1) * 16;
        float num[16];
#pragma unroll
        for (int j = 0; j < 16; ++j) num[j] = 0.f;
        float den = 0.f;
#pragma unroll 4
        for (int d = 0; d < 32; ++d) {
          float qv = Qs[hl * 32 + d][p];
          den += qv * kms[hl * 32 + d];
          const float4* kvr = (const float4*)&kvs[hl][d][e0];
#pragma unroll
          for (int j4 = 0; j4 < 4; ++j4) {
            float4 kvv = kvr[j4];
            num[4 * j4 + 0] += qv * kvv.x; num[4 * j4 + 1] += qv * kvv.y;
            num[4 * j4 + 2] += qv * kvv.z; num[4 * j4 + 3] += qv * kvv.w;
          }
        }
        const float rden = 1.0f / (den + 1e-6f);
#pragma unroll
        for (int j = 0; j < 16; ++j) {
          const int c = hp * 64 + hl * 32 + e0 + j;  // out channel = h*32+e
          const float* pw = pe_w + c * 9;
          float pe = pe_b[c];
#pragma unroll
          for (int dy = 0; dy < 3; ++dy) {
            const int rr = row + dy - 1;
            if (rr < 0 || rr >= HWDIM) continue;
#pragma unroll
            for (int dx = 0; dx < 3; ++dx) {
              const int pp = p + dx - 1;
              if (pp < 0 || pp >= HWDIM) continue;
              pe += pw[dy * 3 + dx] *
                    x[((size_t)b * NCH + c) * NPIX + rr * HWDIM + pp];
            }
          }
          out[((size_t)b * NCH + c) * NPIX + row * HWDIM + p] =
              num[j] * rden + pe;
        }
      }
    }
  }
}

extern "C" void kernel_launch(void* const* d_in, const int* in_sizes, int n_in,
                              void* d_out, int out_size, void* d_ws,
                              size_t ws_size, hipStream_t stream) {
  const float* x    = (const float*)d_in[0];
  const float* qk_w = (const float*)d_in[1];
  const float* qk_b = (const float*)d_in[2];
  const float* pe_w = (const float*)d_in[3];
  const float* pe_b = (const float*)d_in[4];
  float* out = (float*)d_out;
  float* kv  = (float*)d_ws;
  float* km  = kv + KV_FLOATS;

  // atomics accumulate into ws: must re-zero every launch (harness does not
  // re-poison between timed replays)
  hipMemsetAsync(d_ws, 0, (KV_FLOATS + KM_FLOATS) * sizeof(float), stream);

  dim3 g1(16, NB);
  kv_kernel<<<g1, 256, 0, stream>>>(x, qk_w, qk_b, kv, km);

  dim3 g2(28, NB);
  out_kernel<<<g2, 256, 0, stream>>>(x, qk_w, qk_b, pe_w, pe_b, kv, km, out);
}